// Round 3
// baseline (124.040 us; speedup 1.0000x reference)
//
#include <hip/hip_runtime.h>
#include <hip/hip_bf16.h>

// EdgeNetwork fused kernel:
//   out[src[e], i] += sum_{b,j} bond[e,b] * nb[e,j] * K[b, i*64+j]  (+ bias via 17th channel)
// Formulated as (E x 1088) @ (1088 x 64) GEMM, A rows built on-the-fly as bond (x) nb.
// W (1088x64 bf16, fragment-packed) lives in LDS for the whole kernel (139 KiB).
// grid=256 (1 block/CU), 512 threads = 8 waves = 4 edge-groups x 2 N-halves.
// Each wave: one 32x32 mfma_f32_32x32x16_bf16 tile, K-loop of 68 MFMAs.
// Epilogue: coalesced f32 atomicAdd into zeroed output.

#define N_EDGES   100000
#define DIM       64
#define BDIM      16
#define NB_CH     17                    // 16 bond channels + 1 bias channel
#define KSTEPS    68                    // NB_CH*64/16
#define TILE      32
#define NTILES    (N_EDGES / TILE)      // 3125
#define GROUPS    4
#define BLOCK     512
#define GRID      256

#define W_BYTES      (KSTEPS * 2 * 64 * 16)    // 139264: 68 ksteps x 2 halves x 64 lanes x 16B
#define NBQ_BYTES    (TILE * DIM * 2)          // 4096 (bf16, chunk-swizzled)
#define BOND_STRIDE  20                        // bf16 elems per row (padded)
#define BOND_BYTES   (TILE * BOND_STRIDE * 2)  // 1280
#define SRC_BYTES    (TILE * 4)                // 128
#define GROUP_BYTES  (NBQ_BYTES + BOND_BYTES + SRC_BYTES)   // 5504
#define LDS_TOTAL    (W_BYTES + GROUPS * GROUP_BYTES)       // 161280 <= 163840

typedef __bf16 bf16x8 __attribute__((ext_vector_type(8)));
typedef float  f32x16 __attribute__((ext_vector_type(16)));

__global__ __launch_bounds__(BLOCK, 2)
void edge_mfma_kernel(const float* __restrict__ atom,
                      const float* __restrict__ bondf,
                      const int*   __restrict__ pair,
                      const float* __restrict__ kmat,
                      const float* __restrict__ bias,
                      float* __restrict__ out)
{
    extern __shared__ char smem[];
    const int tid = threadIdx.x;

    // ---- stage W into LDS, fragment-packed bf16 ----
    // frag slot f = (s*2+h)*64 + l holds B[k = s*16 + (l>>5)*8 + j][n = h*32 + (l&31)]
    // where global K-row kk = b*64 + jj:  b<16 -> kernel[b][n*64+jj], b==16 -> bias[n*64+jj]
    for (int it = 0; it < (KSTEPS * 2 * 64) / BLOCK; ++it) {   // 17 iters
        int f   = it * BLOCK + tid;
        int fb  = f >> 6;
        int l   = f & 63;
        int s   = fb >> 1, h = fb & 1;
        int kk0 = s * 16 + ((l >> 5) << 3);
        int n   = h * 32 + (l & 31);
        int b   = kk0 >> 6;
        int jj0 = kk0 & 63;
        const float* src = (b < BDIM) ? (kmat + b * (DIM * DIM) + n * DIM + jj0)
                                      : (bias + n * DIM + jj0);
        float4 v0 = *(const float4*)(src);
        float4 v1 = *(const float4*)(src + 4);
        bf16x8 w;
        w[0] = (__bf16)v0.x; w[1] = (__bf16)v0.y; w[2] = (__bf16)v0.z; w[3] = (__bf16)v0.w;
        w[4] = (__bf16)v1.x; w[5] = (__bf16)v1.y; w[6] = (__bf16)v1.z; w[7] = (__bf16)v1.w;
        *(bf16x8*)(smem + f * 16) = w;
    }
    __syncthreads();

    const int g   = tid >> 7;        // edge-group 0..3
    const int tg  = tid & 127;
    const int l   = tid & 63;
    const int wid = tid >> 6;
    const int h   = wid & 1;         // N-half of this wave
    const int ma  = l & 31;          // edge row within tile (MFMA A row)
    const int hi  = l >> 5;

    char*   gbase = smem + W_BYTES + g * GROUP_BYTES;
    char*   nbb   = gbase;                                   // bf16 [32][64], 16B-chunk swizzled
    __bf16* bnd   = (__bf16*)(gbase + NBQ_BYTES);            // bf16 [32][20]
    int*    srcs  = (int*)(gbase + NBQ_BYTES + BOND_BYTES);  // int  [32]

    for (int base = blockIdx.x * GROUPS; base < NTILES; base += gridDim.x * GROUPS) {
        int  tile  = base + g;
        bool valid = tile < NTILES;

        if (valid) {
            // ---- stage this tile's 32 edges: nb (gathered, bf16) + bond (bf16) + src ids
            int m = tg >> 2, p = tg & 3;
            int e = tile * TILE + m;
            int dst = pair[2 * e + 1];
            const float4* ap = (const float4*)(atom + dst * DIM + p * 16);
            float4 a0 = ap[0], a1 = ap[1], a2 = ap[2], a3 = ap[3];
            bf16x8 q0, q1;
            q0[0] = (__bf16)a0.x; q0[1] = (__bf16)a0.y; q0[2] = (__bf16)a0.z; q0[3] = (__bf16)a0.w;
            q0[4] = (__bf16)a1.x; q0[5] = (__bf16)a1.y; q0[6] = (__bf16)a1.z; q0[7] = (__bf16)a1.w;
            q1[0] = (__bf16)a2.x; q1[1] = (__bf16)a2.y; q1[2] = (__bf16)a2.z; q1[3] = (__bf16)a2.w;
            q1[4] = (__bf16)a3.x; q1[5] = (__bf16)a3.y; q1[6] = (__bf16)a3.z; q1[7] = (__bf16)a3.w;
            int sw = m & 7;   // XOR chunk swizzle breaks the 128B-row-stride bank conflict
            *(bf16x8*)(nbb + m * 128 + (((2 * p    ) ^ sw) << 4)) = q0;
            *(bf16x8*)(nbb + m * 128 + (((2 * p + 1) ^ sw) << 4)) = q1;
            if (p == 0) srcs[m] = pair[2 * e];
            if (tg < TILE) {
                int m2 = tg;
                int e2 = tile * TILE + m2;
                const float4* bp = (const float4*)(bondf + e2 * BDIM);
                float4 b0 = bp[0], b1 = bp[1], b2 = bp[2], b3 = bp[3];
                __bf16* br = bnd + m2 * BOND_STRIDE;
                br[0]  = (__bf16)b0.x; br[1]  = (__bf16)b0.y; br[2]  = (__bf16)b0.z; br[3]  = (__bf16)b0.w;
                br[4]  = (__bf16)b1.x; br[5]  = (__bf16)b1.y; br[6]  = (__bf16)b1.z; br[7]  = (__bf16)b1.w;
                br[8]  = (__bf16)b2.x; br[9]  = (__bf16)b2.y; br[10] = (__bf16)b2.z; br[11] = (__bf16)b2.w;
                br[12] = (__bf16)b3.x; br[13] = (__bf16)b3.y; br[14] = (__bf16)b3.z; br[15] = (__bf16)b3.w;
                br[16] = (__bf16)1.0f;           // bias channel weight
            }
        }
        __syncthreads();

        if (valid) {
            f32x16 acc;
            #pragma unroll
            for (int i = 0; i < 16; ++i) acc[i] = 0.0f;

            const char*   nbrow = nbb + ma * 128;
            const int     sw    = ma & 7;
            const __bf16* brow  = bnd + ma * BOND_STRIDE;
            const char*   wbase = smem + (h * 64 + l) * 16;

            for (int b = 0; b < NB_CH; ++b) {          // bond channel = 4 consecutive ksteps
                float bv = (float)brow[b];
                #pragma unroll
                for (int ss = 0; ss < 4; ++ss) {
                    // A frag: lane holds A[ma][hi*8+j] = bond[ma][b] * nb[ma][ss*16+hi*8+j]
                    bf16x8 nv = *(const bf16x8*)(nbrow + (((ss * 2 + hi) ^ sw) << 4));
                    bf16x8 a;
                    #pragma unroll
                    for (int j = 0; j < 8; ++j)
                        a[j] = (__bf16)(bv * (float)nv[j]);
                    bf16x8 w = *(const bf16x8*)(wbase + (b * 4 + ss) * 2048);
                    acc = __builtin_amdgcn_mfma_f32_32x32x16_bf16(a, w, acc, 0, 0, 0);
                }
            }

            // ---- epilogue: D lane mapping col=l&31, row=(r&3)+8*(r>>2)+4*(l>>5)
            int n = h * 32 + (l & 31);
            #pragma unroll
            for (int r = 0; r < 16; ++r) {
                int m = (r & 3) + 8 * (r >> 2) + 4 * hi;
                atomicAdd(out + srcs[m] * DIM + n, acc[r]);
            }
        }
        __syncthreads();
    }
}

extern "C" void kernel_launch(void* const* d_in, const int* in_sizes, int n_in,
                              void* d_out, int out_size, void* d_ws, size_t ws_size,
                              hipStream_t stream)
{
    const float* atom  = (const float*)d_in[0];
    const float* bondf = (const float*)d_in[1];
    const int*   pair  = (const int*)  d_in[2];
    const float* kmat  = (const float*)d_in[3];
    const float* bias  = (const float*)d_in[4];
    float* out = (float*)d_out;

    hipFuncSetAttribute((const void*)edge_mfma_kernel,
                        hipFuncAttributeMaxDynamicSharedMemorySize, LDS_TOTAL);
    hipMemsetAsync(out, 0, (size_t)out_size * sizeof(float), stream);
    edge_mfma_kernel<<<GRID, BLOCK, LDS_TOTAL, stream>>>(atom, bondf, pair, kmat, bias, out);
}